// Round 5
// baseline (205.124 us; speedup 1.0000x reference)
//
#include <hip/hip_runtime.h>
#include <hip/hip_bf16.h>

#define Bn 4096
#define Dk 1024
#define EPSF 1e-7f

typedef float f32x4 __attribute__((ext_vector_type(4)));

// -------- Kernel 1: L2-normalize rows -> fp8 e4m3 (x8 prescale); exact f32 diag; zero sums ----
// prescale by 8 puts element RMS at ~0.25 (good e4m3 mantissa use); compensated exactly by
// multiplying the f32 accumulator by 2^-6 in the gemm epilogue.
__global__ __launch_bounds__(256)
void nrm_kernel(const float4* __restrict__ left, const float4* __restrict__ right,
                unsigned* __restrict__ lnb8, unsigned* __restrict__ rnb8,
                float* __restrict__ diag, float* __restrict__ rowsum,
                float* __restrict__ colsum)
{
    const int row = blockIdx.x;
    const int t = threadIdx.x;
    const int idx = row * (Dk / 4) + t;
    const float4 l = left[idx];
    const float4 r = right[idx];
    float sl = l.x * l.x + l.y * l.y + l.z * l.z + l.w * l.w;
    float sr = r.x * r.x + r.y * r.y + r.z * r.z + r.w * r.w;
    float slr = l.x * r.x + l.y * r.y + l.z * r.z + l.w * r.w;
    #pragma unroll
    for (int off = 1; off < 64; off <<= 1) {
        sl += __shfl_xor(sl, off);
        sr += __shfl_xor(sr, off);
        slr += __shfl_xor(slr, off);
    }
    __shared__ float red[3][4];
    const int wave = t >> 6, lane = t & 63;
    if (lane == 0) { red[0][wave] = sl; red[1][wave] = sr; red[2][wave] = slr; }
    __syncthreads();
    sl = red[0][0] + red[0][1] + red[0][2] + red[0][3];
    sr = red[1][0] + red[1][1] + red[1][2] + red[1][3];
    const float invl = 1.0f / sqrtf(fmaxf(sl, EPSF));
    const float invr = 1.0f / sqrtf(fmaxf(sr, EPSF));
    const float sL = 8.0f * invl;
    const float sR = 8.0f * invr;
    int pkL = __builtin_amdgcn_cvt_pk_fp8_f32(l.x * sL, l.y * sL, 0, false);
    pkL = __builtin_amdgcn_cvt_pk_fp8_f32(l.z * sL, l.w * sL, pkL, true);
    int pkR = __builtin_amdgcn_cvt_pk_fp8_f32(r.x * sR, r.y * sR, 0, false);
    pkR = __builtin_amdgcn_cvt_pk_fp8_f32(r.z * sR, r.w * sR, pkR, true);
    lnb8[idx] = (unsigned)pkL;
    rnb8[idx] = (unsigned)pkR;
    if (t == 0) {
        const float d = red[2][0] + red[2][1] + red[2][2] + red[2][3];
        diag[row] = d * invl * invr;
        rowsum[row] = 0.f;
        colsum[row] = 0.f;
    }
}

// -------- Kernel 2: S = ln . rn^T, fp8 mfma_f32_16x16x32, NO LDS, NO BARRIERS ----
// Fragments load straight from global (L1/L2-resident; per-block slices are 128 KB).
// A-frag load: 64 lanes cover 16 rows x 32 B contiguous; ks=0/1 consume the two
// halves of each 64-B line -> no overfetch. No __syncthreads => no vmcnt(0) drain;
// waves software-pipeline loads against MFMAs freely (AITER-style K-loop).
// 128x128 block tile, 4 waves 2x2, each wave 64x64 = 4x4 frags, BK=64 (16 iters).
__global__ __launch_bounds__(256, 2)
void gemm_sm_kernel(const unsigned char* __restrict__ lnb8,
                    const unsigned char* __restrict__ rnb8,
                    const float* __restrict__ temp,
                    float* __restrict__ rowsum, float* __restrict__ colsum)
{
    const int tid = threadIdx.x;
    const int wave = tid >> 6;
    const int lane = tid & 63;
    const int bm0 = blockIdx.y * 128;
    const int bn0 = blockIdx.x * 128;

    const int wm = (wave & 1) * 64;
    const int wn = (wave >> 1) * 64;
    const int quad = lane >> 4;
    const int r16 = lane & 15;

    // per-fragment base pointers (8 addr pairs in SGPR/VGPR, then 13-bit imm offsets)
    const unsigned char* pA[4];
    const unsigned char* pB[4];
    #pragma unroll
    for (int i = 0; i < 4; ++i) {
        pA[i] = lnb8 + (size_t)(bm0 + wm + i * 16 + r16) * Dk + quad * 8;
        pB[i] = rnb8 + (size_t)(bn0 + wn + i * 16 + r16) * Dk + quad * 8;
    }

    f32x4 acc[4][4];
    #pragma unroll
    for (int i = 0; i < 4; ++i)
        #pragma unroll
        for (int j = 0; j < 4; ++j)
            acc[i][j] = (f32x4){0.f, 0.f, 0.f, 0.f};

    #pragma unroll 2
    for (int k0 = 0; k0 < Dk; k0 += 64) {
        long af[2][4], bf[2][4];
        #pragma unroll
        for (int ks = 0; ks < 2; ++ks)
            #pragma unroll
            for (int i = 0; i < 4; ++i) {
                af[ks][i] = *(const long*)(pA[i] + k0 + ks * 32);
                bf[ks][i] = *(const long*)(pB[i] + k0 + ks * 32);
            }
        #pragma unroll
        for (int ks = 0; ks < 2; ++ks)
            #pragma unroll
            for (int mi = 0; mi < 4; ++mi)
                #pragma unroll
                for (int ni = 0; ni < 4; ++ni)
                    acc[mi][ni] = __builtin_amdgcn_mfma_f32_16x16x32_fp8_fp8(
                        af[ks][mi], bf[ks][ni], acc[mi][ni], 0, 0, 0);
    }

    // epilogue: undo the 8x8 prescale (2^-6, exact), then p = exp(scale*s - scale)
    // (|s|<=1 so scale is a valid softmax max-bound; row sums of exp are exact-enough)
    const float scale = __expf(temp[0]);
    const float dq = 0.015625f * scale;  // 2^-6 * scale
    #pragma unroll
    for (int mi = 0; mi < 4; ++mi)
        #pragma unroll
        for (int ni = 0; ni < 4; ++ni)
            #pragma unroll
            for (int r = 0; r < 4; ++r)
                acc[mi][ni][r] = __expf(dq * acc[mi][ni][r] - scale);

    // C/D layout: col = lane&15, row = quad*4 + reg
    #pragma unroll
    for (int mi = 0; mi < 4; ++mi) {
        #pragma unroll
        for (int r = 0; r < 4; ++r) {
            float v = acc[mi][0][r] + acc[mi][1][r] + acc[mi][2][r] + acc[mi][3][r];
            v += __shfl_xor(v, 1);
            v += __shfl_xor(v, 2);
            v += __shfl_xor(v, 4);
            v += __shfl_xor(v, 8);
            if (r16 == 0)
                atomicAdd(&rowsum[bm0 + wm + mi * 16 + quad * 4 + r], v);
        }
    }
    #pragma unroll
    for (int ni = 0; ni < 4; ++ni) {
        float v = 0.f;
        #pragma unroll
        for (int mi = 0; mi < 4; ++mi)
            #pragma unroll
            for (int r = 0; r < 4; ++r)
                v += acc[mi][ni][r];
        v += __shfl_xor(v, 16);
        v += __shfl_xor(v, 32);
        if (quad == 0)
            atomicAdd(&colsum[bn0 + wn + ni * 16 + r16], v);
    }
}

// -------- Kernel 3: final scalar loss --------
__global__ __launch_bounds__(256)
void loss_kernel(const float* __restrict__ diag, const float* __restrict__ rowsum,
                 const float* __restrict__ colsum, const float* __restrict__ temp,
                 float* __restrict__ out)
{
    const int t = threadIdx.x;
    const float scale = __expf(temp[0]);
    float dL = 0.f, dR = 0.f;
    for (int i = t; i < Bn; i += 256) {
        const float e = __expf(scale * (diag[i] - 1.0f));
        dL += e * __builtin_amdgcn_rcpf(rowsum[i]);
        dR += e * __builtin_amdgcn_rcpf(colsum[i]);
    }
    #pragma unroll
    for (int off = 1; off < 64; off <<= 1) {
        dL += __shfl_xor(dL, off);
        dR += __shfl_xor(dR, off);
    }
    __shared__ float rd[2][4];
    const int wave = t >> 6, lane = t & 63;
    if (lane == 0) { rd[0][wave] = dL; rd[1][wave] = dR; }
    __syncthreads();
    if (t == 0) {
        dL = rd[0][0] + rd[0][1] + rd[0][2] + rd[0][3];
        dR = rd[1][0] + rd[1][1] + rd[1][2] + rd[1][3];
        const float logeps = logf(EPSF);
        const float log1m = logf(1.0f - EPSF);
        const float lossL = -(dL * log1m + ((float)Bn - dL) * logeps);
        const float lossR = -(dR * log1m + ((float)Bn - dR) * logeps);
        out[0] = (lossL + lossR) * 0.5f / (float)Bn;
    }
}

extern "C" void kernel_launch(void* const* d_in, const int* in_sizes, int n_in,
                              void* d_out, int out_size, void* d_ws, size_t ws_size,
                              hipStream_t stream) {
    (void)in_sizes; (void)n_in; (void)out_size; (void)ws_size;
    const float* left = (const float*)d_in[0];
    const float* right = (const float*)d_in[1];
    const float* temp = (const float*)d_in[2];

    char* ws = (char*)d_ws;
    unsigned char* lnb8 = (unsigned char*)ws;                       // 4 MiB
    unsigned char* rnb8 = (unsigned char*)(ws + (size_t)Bn * Dk);   // 4 MiB
    float* diag = (float*)(ws + 2 * (size_t)Bn * Dk);
    float* rowsum = diag + Bn;
    float* colsum = rowsum + Bn;

    nrm_kernel<<<Bn, 256, 0, stream>>>((const float4*)left, (const float4*)right,
                                       (unsigned*)lnb8, (unsigned*)rnb8, diag, rowsum, colsum);
    dim3 g2(Bn / 128, Bn / 128);
    gemm_sm_kernel<<<g2, 256, 0, stream>>>(lnb8, rnb8, temp, rowsum, colsum);
    loss_kernel<<<1, 256, 0, stream>>>(diag, rowsum, colsum, temp, (float*)d_out);
}

// Round 6
// 119.093 us; speedup vs baseline: 1.7224x; 1.7224x over previous
//
#include <hip/hip_runtime.h>
#include <hip/hip_bf16.h>

#define Bn 4096
#define Dk 1024
#define EPSF 1e-7f

typedef float f32x4 __attribute__((ext_vector_type(4)));

__device__ __forceinline__ void async_copy16(const void* g, void* l) {
    __builtin_amdgcn_global_load_lds((__attribute__((address_space(1))) void*)(uintptr_t)g,
                                     (__attribute__((address_space(3))) void*)l, 16, 0, 0);
}

// -------- Kernel 1: L2-normalize rows -> fp8 e4m3 (x8 prescale); exact f32 diag; zero sums ----
__global__ __launch_bounds__(256)
void nrm_kernel(const float4* __restrict__ left, const float4* __restrict__ right,
                unsigned* __restrict__ lnb8, unsigned* __restrict__ rnb8,
                float* __restrict__ diag, float* __restrict__ rowsum,
                float* __restrict__ colsum)
{
    const int row = blockIdx.x;
    const int t = threadIdx.x;
    const int idx = row * (Dk / 4) + t;
    const float4 l = left[idx];
    const float4 r = right[idx];
    float sl = l.x * l.x + l.y * l.y + l.z * l.z + l.w * l.w;
    float sr = r.x * r.x + r.y * r.y + r.z * r.z + r.w * r.w;
    float slr = l.x * r.x + l.y * r.y + l.z * r.z + l.w * r.w;
    #pragma unroll
    for (int off = 1; off < 64; off <<= 1) {
        sl += __shfl_xor(sl, off);
        sr += __shfl_xor(sr, off);
        slr += __shfl_xor(slr, off);
    }
    __shared__ float red[3][4];
    const int wave = t >> 6, lane = t & 63;
    if (lane == 0) { red[0][wave] = sl; red[1][wave] = sr; red[2][wave] = slr; }
    __syncthreads();
    sl = red[0][0] + red[0][1] + red[0][2] + red[0][3];
    sr = red[1][0] + red[1][1] + red[1][2] + red[1][3];
    const float invl = 1.0f / sqrtf(fmaxf(sl, EPSF));
    const float invr = 1.0f / sqrtf(fmaxf(sr, EPSF));
    const float sL = 8.0f * invl;
    const float sR = 8.0f * invr;
    int pkL = __builtin_amdgcn_cvt_pk_fp8_f32(l.x * sL, l.y * sL, 0, false);
    pkL = __builtin_amdgcn_cvt_pk_fp8_f32(l.z * sL, l.w * sL, pkL, true);
    int pkR = __builtin_amdgcn_cvt_pk_fp8_f32(r.x * sR, r.y * sR, 0, false);
    pkR = __builtin_amdgcn_cvt_pk_fp8_f32(r.z * sR, r.w * sR, pkR, true);
    lnb8[idx] = (unsigned)pkL;
    rnb8[idx] = (unsigned)pkR;
    if (t == 0) {
        const float d = red[2][0] + red[2][1] + red[2][2] + red[2][3];
        diag[row] = d * invl * invr;
        rowsum[row] = 0.f;
        colsum[row] = 0.f;
    }
}

// -------- Kernel 2: S = ln . rn^T, fp8 16x16x32 MFMA, PING-PONG LDS, raw-barrier pipeline ----
// R4 structure + double-buffered LDS. The key change vs __syncthreads: inline-asm
// "s_waitcnt vmcnt(4); s_barrier" waits ONLY the previous tile's 4 global_load_lds
// (prefetch of the next tile stays in flight across the barrier — AITER-style), and the
// post-compute barrier is execution-only (no drain). K wraps on the last prefetch so the
// outstanding-load count is uniformly 4.
__global__ __launch_bounds__(256, 2)
void gemm_sm_kernel(const unsigned char* __restrict__ lnb8,
                    const unsigned char* __restrict__ rnb8,
                    const float* __restrict__ temp,
                    float* __restrict__ rowsum, float* __restrict__ colsum)
{
    __shared__ __align__(16) unsigned char As[2][128 * 64];
    __shared__ __align__(16) unsigned char Bs[2][128 * 64];

    const int tid = threadIdx.x;
    const int wave = tid >> 6;
    const int lane = tid & 63;
    const int bm0 = blockIdx.y * 128;
    const int bn0 = blockIdx.x * 128;

    // ---- staging: wave w stages rows [32w, 32w+32), 2 insts of 16 rows per matrix
    const int srow = lane >> 2;          // row within 16-row inst group
    const int sj = lane & 3;             // chunk16 slot within 64-B row
    int goff[2];                         // global byte offset (row*Dk + swizzled col)
    int lofs[2];                         // LDS base offset (wave-uniform)
    #pragma unroll
    for (int i = 0; i < 2; ++i) {
        const int rloc = wave * 32 + i * 16 + srow;
        goff[i] = rloc * Dk + 16 * (sj ^ ((rloc >> 1) & 3));   // even-key swizzle
        lofs[i] = (wave * 32 + i * 16) * 64;
    }
    const unsigned char* baseA = lnb8 + (size_t)bm0 * Dk;
    const unsigned char* baseB = rnb8 + (size_t)bn0 * Dk;

    // ---- compute-side: 16x16x32 fp8
    const int wm = (wave & 1) * 64;
    const int wn = (wave >> 1) * 64;
    const int quad = lane >> 4;
    const int r16 = lane & 15;
    const int key = r16 & 6;
    int aoff[4], boff[4];
    #pragma unroll
    for (int i = 0; i < 4; ++i) {
        aoff[i] = (wm + i * 16 + r16) * 64 + 8 * (quad ^ key);
        boff[i] = (wn + i * 16 + r16) * 64 + 8 * (quad ^ key);
    }
    const int ks1d = 8 * ((4 + quad) ^ key) - 8 * (quad ^ key);

    f32x4 acc[4][4];
    #pragma unroll
    for (int i = 0; i < 4; ++i)
        #pragma unroll
        for (int j = 0; j < 4; ++j)
            acc[i][j] = (f32x4){0.f, 0.f, 0.f, 0.f};

    // prologue: stage tile 0 into buffer 0
    #pragma unroll
    for (int i = 0; i < 2; ++i) {
        async_copy16(baseA + goff[i], &As[0][lofs[i]]);
        async_copy16(baseB + goff[i], &Bs[0][lofs[i]]);
    }

    #pragma unroll 2
    for (int it = 0; it < 16; ++it) {
        const int cur = it & 1;
        const int nxt = cur ^ 1;
        const int knext = ((it + 1) & 15) * 64;   // wraps on last iter (dummy reload)
        #pragma unroll
        for (int i = 0; i < 2; ++i) {
            async_copy16(baseA + goff[i] + knext, &As[nxt][lofs[i]]);
            async_copy16(baseB + goff[i] + knext, &Bs[nxt][lofs[i]]);
        }
        // wait only the PREVIOUS tile's 4 loads; prefetch stays in flight
        asm volatile("s_waitcnt vmcnt(4)\n\ts_barrier" ::: "memory");
        #pragma unroll
        for (int ks = 0; ks < 2; ++ks) {
            const int d = ks ? ks1d : 0;
            long af[4], bf[4];
            #pragma unroll
            for (int i = 0; i < 4; ++i) af[i] = *(const long*)(&As[cur][aoff[i] + d]);
            #pragma unroll
            for (int i = 0; i < 4; ++i) bf[i] = *(const long*)(&Bs[cur][boff[i] + d]);
            #pragma unroll
            for (int mi = 0; mi < 4; ++mi)
                #pragma unroll
                for (int ni = 0; ni < 4; ++ni)
                    acc[mi][ni] = __builtin_amdgcn_mfma_f32_16x16x32_fp8_fp8(
                        af[mi], bf[ni], acc[mi][ni], 0, 0, 0);
        }
        // execution-only barrier: everyone done reading `cur` before it is restaged
        asm volatile("s_barrier" ::: "memory");
    }

    // epilogue: undo the 8x8 prescale (2^-6, exact), then p = exp(scale*s - scale)
    const float scale = __expf(temp[0]);
    const float dq = 0.015625f * scale;  // 2^-6 * scale
    #pragma unroll
    for (int mi = 0; mi < 4; ++mi)
        #pragma unroll
        for (int ni = 0; ni < 4; ++ni)
            #pragma unroll
            for (int r = 0; r < 4; ++r)
                acc[mi][ni][r] = __expf(dq * acc[mi][ni][r] - scale);

    // C/D layout: col = lane&15, row = quad*4 + reg
    #pragma unroll
    for (int mi = 0; mi < 4; ++mi) {
        #pragma unroll
        for (int r = 0; r < 4; ++r) {
            float v = acc[mi][0][r] + acc[mi][1][r] + acc[mi][2][r] + acc[mi][3][r];
            v += __shfl_xor(v, 1);
            v += __shfl_xor(v, 2);
            v += __shfl_xor(v, 4);
            v += __shfl_xor(v, 8);
            if (r16 == 0)
                atomicAdd(&rowsum[bm0 + wm + mi * 16 + quad * 4 + r], v);
        }
    }
    #pragma unroll
    for (int ni = 0; ni < 4; ++ni) {
        float v = 0.f;
        #pragma unroll
        for (int mi = 0; mi < 4; ++mi)
            #pragma unroll
            for (int r = 0; r < 4; ++r)
                v += acc[mi][ni][r];
        v += __shfl_xor(v, 16);
        v += __shfl_xor(v, 32);
        if (quad == 0)
            atomicAdd(&colsum[bn0 + wn + ni * 16 + r16], v);
    }
}

// -------- Kernel 3: final scalar loss --------
__global__ __launch_bounds__(256)
void loss_kernel(const float* __restrict__ diag, const float* __restrict__ rowsum,
                 const float* __restrict__ colsum, const float* __restrict__ temp,
                 float* __restrict__ out)
{
    const int t = threadIdx.x;
    const float scale = __expf(temp[0]);
    float dL = 0.f, dR = 0.f;
    for (int i = t; i < Bn; i += 256) {
        const float e = __expf(scale * (diag[i] - 1.0f));
        dL += e * __builtin_amdgcn_rcpf(rowsum[i]);
        dR += e * __builtin_amdgcn_rcpf(colsum[i]);
    }
    #pragma unroll
    for (int off = 1; off < 64; off <<= 1) {
        dL += __shfl_xor(dL, off);
        dR += __shfl_xor(dR, off);
    }
    __shared__ float rd[2][4];
    const int wave = t >> 6, lane = t & 63;
    if (lane == 0) { rd[0][wave] = dL; rd[1][wave] = dR; }
    __syncthreads();
    if (t == 0) {
        dL = rd[0][0] + rd[0][1] + rd[0][2] + rd[0][3];
        dR = rd[1][0] + rd[1][1] + rd[1][2] + rd[1][3];
        const float logeps = logf(EPSF);
        const float log1m = logf(1.0f - EPSF);
        const float lossL = -(dL * log1m + ((float)Bn - dL) * logeps);
        const float lossR = -(dR * log1m + ((float)Bn - dR) * logeps);
        out[0] = (lossL + lossR) * 0.5f / (float)Bn;
    }
}

extern "C" void kernel_launch(void* const* d_in, const int* in_sizes, int n_in,
                              void* d_out, int out_size, void* d_ws, size_t ws_size,
                              hipStream_t stream) {
    (void)in_sizes; (void)n_in; (void)out_size; (void)ws_size;
    const float* left = (const float*)d_in[0];
    const float* right = (const float*)d_in[1];
    const float* temp = (const float*)d_in[2];

    char* ws = (char*)d_ws;
    unsigned char* lnb8 = (unsigned char*)ws;                       // 4 MiB
    unsigned char* rnb8 = (unsigned char*)(ws + (size_t)Bn * Dk);   // 4 MiB
    float* diag = (float*)(ws + 2 * (size_t)Bn * Dk);
    float* rowsum = diag + Bn;
    float* colsum = rowsum + Bn;

    nrm_kernel<<<Bn, 256, 0, stream>>>((const float4*)left, (const float4*)right,
                                       (unsigned*)lnb8, (unsigned*)rnb8, diag, rowsum, colsum);
    dim3 g2(Bn / 128, Bn / 128);
    gemm_sm_kernel<<<g2, 256, 0, stream>>>(lnb8, rnb8, temp, rowsum, colsum);
    loss_kernel<<<1, 256, 0, stream>>>(diag, rowsum, colsum, temp, (float*)d_out);
}